// Round 16
// baseline (28.313 us; speedup 1.0000x reference)
//
#include <hip/hip_runtime.h>

// ---------------------------------------------------------------------------
// qprecomp (1 block, 64 threads = ONE wave): builds the four 81-element
// coefficient tensors C[mi][q]:  z_q = sum_mi C[mi][q] * prod_q w_q[m_q],
// w_q = (1+cos x_q, sin x_q, 1-cos x_q), 1/16 folded into C.
//
// psi = D r (real tensor-product r), final = U r, U = V*D;
// M^q_jk = sum_i sign_q(i) Re(conj(U_ij) U_ik), binned by per-qubit
// signature m_q = j_q + k_q in {0,1,2}.
//
// Round-14 lesson: the old 256-thread qprecomp was a 21-barrier serial chain
// of tiny LDS ops across 4 waves (~5-10 us on one CU). Here lane j (<16)
// holds column j of U entirely in REGISTERS (all indices static): Rot gates
// are row-pair ops (lane-local), CNOTs are row permutations (lane-local
// register swaps) -> the whole gate chain needs NO LDS and NO barriers.
// Only the Gram stage crosses lanes, via LDS with single-wave barriers
// (s_barrier with 1 wave/block = pipeline drain, near-free).
// ---------------------------------------------------------------------------
__global__ __launch_bounds__(64) void qprecomp(const float* __restrict__ params,
                                               float* __restrict__ C) {
  __shared__ float colR[16][16];   // colR[j][i] = Re U_ij
  __shared__ float colI[16][16];
  __shared__ float4 S4[256];       // per ordered pair (j,k): 4 signed sums
  const int t = threadIdx.x;

  // ---- Phase 1: registers. Column t of U = V*D (lanes >=16 compute junk).
  float uR[16], uI[16];
  {
    const int pc = __popc(t) & 3;
    const float dre = (pc == 0) ? 1.0f : (pc == 2 ? -1.0f : 0.0f);
    const float dim = (pc == 1) ? -1.0f : (pc == 3 ? 1.0f : 0.0f);
#pragma unroll
    for (int i = 0; i < 16; ++i) {
      uR[i] = (i == t) ? dre : 0.0f;
      uI[i] = (i == t) ? dim : 0.0f;
    }
  }

#pragma unroll
  for (int l = 0; l < 3; ++l) {
#pragma unroll
    for (int q = 0; q < 4; ++q) {
      const int g = l * 4 + q;
      const float phi = params[g * 3 + 0];
      const float th  = params[g * 3 + 1];
      const float om  = params[g * 3 + 2];
      const float sa = __sinf(0.5f * (phi + om)), ca = __cosf(0.5f * (phi + om));
      const float sb = __sinf(0.5f * (phi - om)), cb = __cosf(0.5f * (phi - om));
      const float s2 = __sinf(0.5f * th),         c2 = __cosf(0.5f * th);
      const float m00r =  c2 * ca, m00i = -c2 * sa;   // m00 = e^{-i a} c
      const float m01r = -s2 * cb, m01i = -s2 * sb;   // m01 = -e^{+i b} s
      const float m10r =  s2 * cb, m10i = -s2 * sb;   // m10 =  e^{-i b} s
      const float m11r =  c2 * ca, m11i =  c2 * sa;   // m11 = e^{+i a} c
      const int B = 3 - q;                            // qubit q = bit (3-q)
#pragma unroll
      for (int p = 0; p < 8; ++p) {
        const int i0 = ((p >> B) << (B + 1)) | (p & ((1 << B) - 1));
        const int i1 = i0 | (1 << B);
        const float a0r = uR[i0], a0i = uI[i0];
        const float a1r = uR[i1], a1i = uI[i1];
        uR[i0] = m00r * a0r - m00i * a0i + m01r * a1r - m01i * a1i;
        uI[i0] = m00r * a0i + m00i * a0r + m01r * a1i + m01i * a1r;
        uR[i1] = m10r * a0r - m10i * a0i + m11r * a1r - m11i * a1i;
        uI[i1] = m10r * a0i + m10i * a0r + m11r * a1i + m11i * a1r;
      }
    }
    // CNOT chain q -> q+1: rows with control bit set get target bit flipped
#pragma unroll
    for (int q = 0; q < 3; ++q) {
      const int Bc = 3 - q, Bt = 2 - q;
#pragma unroll
      for (int i = 0; i < 16; ++i) {
        if ((((i >> Bc) & 1) == 1) && (((i >> Bt) & 1) == 0)) {
          const int i2 = i | (1 << Bt);
          const float tr = uR[i], ti = uI[i];
          uR[i] = uR[i2]; uI[i] = uI[i2];
          uR[i2] = tr;    uI[i2] = ti;
        }
      }
    }
  }

  // ---- Phase 2: publish columns to LDS (single-wave barrier, near-free)
  if (t < 16) {
#pragma unroll
    for (int i = 0; i < 16; ++i) { colR[t][i] = uR[i]; colI[t][i] = uI[i]; }
  }
  __syncthreads();

  // ---- Phase 3: Gram over 256 ordered pairs, 4 per lane
#pragma unroll
  for (int it = 0; it < 4; ++it) {
    const int pp = t + it * 64;
    const int jj = pp >> 4, k = pp & 15;
    float s0 = 0.f, s1 = 0.f, s2 = 0.f, s3 = 0.f;
#pragma unroll
    for (int i = 0; i < 16; ++i) {
      const float pr = colR[jj][i] * colR[k][i] + colI[jj][i] * colI[k][i];
      s0 += ((i >> 3) & 1) ? -pr : pr;   // qubit 0 = bit 3
      s1 += ((i >> 2) & 1) ? -pr : pr;
      s2 += ((i >> 1) & 1) ? -pr : pr;
      s3 += ( i       & 1) ? -pr : pr;
    }
    S4[pp] = make_float4(s0, s1, s2, s3);
  }
  __syncthreads();

  // ---- Phase 4: fold ordered pairs into the 81 signature bins
  for (int bin = t; bin < 81; bin += 64) {
    const int m0 = bin / 27, m1 = (bin / 9) % 3, m2 = (bin / 3) % 3, m3 = bin % 3;
    const int m[4] = { m0, m1, m2, m3 };
    float a0 = 0.f, a1 = 0.f, a2 = 0.f, a3 = 0.f;
    for (int c = 0; c < 16; ++c) {
      int jj = 0, kk = 0; bool ok = true;
#pragma unroll
      for (int q = 0; q < 4; ++q) {
        int jb, kb;
        if (m[q] == 1) { jb = (c >> q) & 1; kb = 1 - jb; }
        else { jb = kb = (m[q] >> 1); if ((c >> q) & 1) ok = false; }
        jj |= jb << (3 - q); kk |= kb << (3 - q);
      }
      if (!ok) continue;
      const float4 sv = S4[jj * 16 + kk];
      a0 += sv.x; a1 += sv.y; a2 += sv.z; a3 += sv.w;
    }
    C[bin * 4 + 0] = a0 * 0.0625f;   // fold 1/16 normalization of w
    C[bin * 4 + 1] = a1 * 0.0625f;
    C[bin * 4 + 2] = a2 * 0.0625f;
    C[bin * 4 + 3] = a3 * 0.0625f;
  }
}

// ---------------------------------------------------------------------------
// qeval: the empirically-fastest eval structure (rounds 1/6: 22.98/23.17 us
// total): 2 patches/thread, C read via uniform global loads with static
// indices, flat 81-term loop, everything fully unrolled (no scratch).
// ---------------------------------------------------------------------------
__device__ __forceinline__ void build_t(const float4 a, float* t01, float* t23) {
  const float s0 = __sinf(a.x), c0 = __cosf(a.x);
  const float s1 = __sinf(a.y), c1 = __cosf(a.y);
  const float s2 = __sinf(a.z), c2 = __cosf(a.z);
  const float s3 = __sinf(a.w), c3 = __cosf(a.w);
  const float w0[3] = { 1.0f + c0, s0, 1.0f - c0 };
  const float w1[3] = { 1.0f + c1, s1, 1.0f - c1 };
  const float w2[3] = { 1.0f + c2, s2, 1.0f - c2 };
  const float w3[3] = { 1.0f + c3, s3, 1.0f - c3 };
#pragma unroll
  for (int i = 0; i < 3; ++i)
#pragma unroll
    for (int jj = 0; jj < 3; ++jj) {
      t01[i * 3 + jj] = w0[i] * w1[jj];
      t23[i * 3 + jj] = w2[i] * w3[jj];
    }
}

__global__ __launch_bounds__(256) void qeval(const float4* __restrict__ x4,
                                             const float4* __restrict__ C4,
                                             float4* __restrict__ out,
                                             int half) {
  const int gid = blockIdx.x * 256 + threadIdx.x;
  float tA01[9], tA23[9], tB01[9], tB23[9];
  build_t(x4[gid], tA01, tA23);
  build_t(x4[gid + half], tB01, tB23);

  float zA0 = 0.f, zA1 = 0.f, zA2 = 0.f, zA3 = 0.f;
  float zB0 = 0.f, zB1 = 0.f, zB2 = 0.f, zB3 = 0.f;
#pragma unroll
  for (int a = 0; a < 9; ++a) {
#pragma unroll
    for (int b = 0; b < 9; ++b) {
      const float4 c = C4[a * 9 + b];   // uniform-address global load
      const float pA = tA01[a] * tA23[b];
      const float pB = tB01[a] * tB23[b];
      zA0 = fmaf(c.x, pA, zA0); zA1 = fmaf(c.y, pA, zA1);
      zA2 = fmaf(c.z, pA, zA2); zA3 = fmaf(c.w, pA, zA3);
      zB0 = fmaf(c.x, pB, zB0); zB1 = fmaf(c.y, pB, zB1);
      zB2 = fmaf(c.z, pB, zB2); zB3 = fmaf(c.w, pB, zB3);
    }
  }
  out[gid]        = make_float4(zA0, zA1, zA2, zA3);
  out[gid + half] = make_float4(zB0, zB1, zB2, zB3);
}

extern "C" void kernel_launch(void* const* d_in, const int* in_sizes, int n_in,
                              void* d_out, int out_size, void* d_ws, size_t ws_size,
                              hipStream_t stream) {
  const float* x      = (const float*)d_in[0];
  const float* params = (const float*)d_in[1];
  float* C = (float*)d_ws;              // 324 floats of scratch

  qprecomp<<<1, 64, 0, stream>>>(params, C);

  const int M      = in_sizes[0] / 4;   // 1,048,576 patches
  const int half   = M / 2;             // 524,288 threads, 2 elems each
  const int blocks = half / 256;        // 2048 blocks
  qeval<<<blocks, 256, 0, stream>>>((const float4*)x, (const float4*)C,
                                    (float4*)d_out, half);
}